// Round 3
// baseline (28.142 us; speedup 1.0000x reference)
//
#include <hip/hip_runtime.h>
#include <math.h>

// PhysicalHarmonicResonanceSystem:
//   idx = d % NP;  p = primes[idx]
//   freq = p * (phi*pi/D) * sigmoid(rscale[idx]) * E
//   angle = pshift[idx] + tm_b * 2*pi,  tm_b = (hash_b % 1000)/1000
//   spec[b,d] = freq * (1 + 0.1*sin(angle));  row-normalize to ||row|| = E
//
// Round 3 insight: in float4 units, pattern index of position o is o%25.
// If a lane strides by 50 float4s, its pattern index is CONSTANT (= lane%25).
// => lanes 0..49 hold one float4 value in a register (via 4 shuffles) and the
// store loop is pure coalesced stores: for(o=lane;o<nv;o+=50) out4[o]=v;
// No LDS, no barriers, no per-iteration mod bookkeeping. Fill-kernel-like.

#define PHI_PI  5.083203692315259f   // ((1+sqrt(5))/2) * pi
#define TWO_PI  6.2831853071795864769f

__global__ __launch_bounds__(256) void phrs_kernel(
    const int*   __restrict__ token_hash,
    const int*   __restrict__ primes,
    const float* __restrict__ rscales,
    const float* __restrict__ pshifts,
    const float* __restrict__ energy,
    float*       __restrict__ out,
    int B, int D, int NP)
{
    const int w    = threadIdx.x >> 6;    // wave id in block
    const int lane = threadIdx.x & 63;
    const int b    = blockIdx.x * 4 + w;  // one row per wave
    if (b >= B) return;                   // wave-uniform; no block sync anywhere

    const float E = energy[0];

    // ---- lanes 0..NP-1 compute the NP distinct spectrum values ----
    float s = 0.0f;
    if (lane < NP) {
        const float tm    = (float)(token_hash[b] % 1000) * 1e-3f;
        const float p     = (float)primes[lane];
        const float sig   = 1.0f / (1.0f + expf(-rscales[lane]));
        const float freq  = p * (PHI_PI / (float)D) * sig * E;
        const float angle = pshifts[lane] + tm * TWO_PI;
        s = freq * (1.0f + 0.1f * sinf(angle));
    }

    // ---- norm: weighted sum of squares, cnt_j = D/NP + (j < D%NP) ----
    const int q = D / NP, r = D % NP;
    float red = (lane < NP) ? (float)(q + (lane < r ? 1 : 0)) * s * s : 0.0f;
    #pragma unroll
    for (int off = 32; off; off >>= 1)
        red += __shfl_xor(red, off, 64);
    const float inv = (red > 0.0f) ? (E / sqrtf(red)) : 1.0f;

    if (NP == 50 && (D & 3) == 0) {
        // ---- per-lane constant float4: components s[(4*lane+c) % 50] ----
        // (all 64 lanes run the shuffles; sources are lanes 0..49)
        int i0 = (4 * lane) % 50;
        int i1 = i0 + 1; if (i1 >= 50) i1 -= 50;
        int i2 = i0 + 2; if (i2 >= 50) i2 -= 50;
        int i3 = i0 + 3; if (i3 >= 50) i3 -= 50;
        float4 v;
        v.x = __shfl(s, i0, 64) * inv;
        v.y = __shfl(s, i1, 64) * inv;
        v.z = __shfl(s, i2, 64) * inv;
        v.w = __shfl(s, i3, 64) * inv;

        // ---- pure store stream: lane's pattern index (o%25) is constant ----
        if (lane < 50) {
            float4* __restrict__ out4 = reinterpret_cast<float4*>(out);
            const int nv = D >> 2;
            const size_t base = (size_t)b * (size_t)nv;
            #pragma unroll 8
            for (int o = lane; o < nv; o += 50)
                out4[base + o] = v;
        }
    } else {
        // generic fallback (not hit for D=8192, NP=50): gather via shuffle
        const size_t rowbase = (size_t)b * (size_t)D;
        for (int i = lane; i < D; i += 64) {
            float sv = __shfl(s, i % NP, 64);
            out[rowbase + i] = sv * inv;
        }
    }
}

extern "C" void kernel_launch(void* const* d_in, const int* in_sizes, int n_in,
                              void* d_out, int out_size, void* d_ws, size_t ws_size,
                              hipStream_t stream) {
    const int*   token_hash = (const int*)  d_in[0];
    const int*   primes     = (const int*)  d_in[1];
    const float* rscales    = (const float*)d_in[2];
    const float* pshifts    = (const float*)d_in[3];
    const float* energy     = (const float*)d_in[4];
    float*       out        = (float*)      d_out;

    const int B  = in_sizes[0];
    const int NP = in_sizes[1];
    const int D  = out_size / B;

    const int blocks = (B + 3) / 4;   // one row per wave, 4 waves per block
    phrs_kernel<<<dim3(blocks), dim3(256), 0, stream>>>(
        token_hash, primes, rscales, pshifts, energy, out, B, D, NP);
}

// Round 5
// 27.164 us; speedup vs baseline: 1.0360x; 1.0360x over previous
//
#include <hip/hip_runtime.h>
#include <math.h>

// PhysicalHarmonicResonanceSystem:
//   idx = d % NP;  p = primes[idx]
//   freq = p * (phi*pi/D) * sigmoid(rscale[idx]) * E
//   angle = pshift[idx] + tm_b * 2*pi,  tm_b = (hash_b % 1000)/1000
//   spec[b,d] = freq * (1 + 0.1*sin(angle));  row-normalize to ||row|| = E
//
// Structure (best of rounds 1-3): one row per wave, pattern of 25 float4s in
// per-wave LDS slot, 64-lane 1024B coalesced stores with incremental mod-25.
// Round 5 = round 4 with the compile fix: __builtin_nontemporal_store needs a
// native vector type, not HIP_vector_type -> use ext_vector_type(4) float.

#define PHI_PI  5.083203692315259f   // ((1+sqrt(5))/2) * pi
#define TWO_PI  6.2831853071795864769f

typedef float f32x4 __attribute__((ext_vector_type(4)));

__global__ __launch_bounds__(256) void phrs_kernel(
    const int*   __restrict__ token_hash,
    const int*   __restrict__ primes,
    const float* __restrict__ rscales,
    const float* __restrict__ pshifts,
    const float* __restrict__ energy,
    float*       __restrict__ out,
    int B, int D, int NP)
{
    __shared__ f32x4 s_pat[4][32];        // per-wave pattern slot (25 used)

    const int w    = threadIdx.x >> 6;    // wave id in block
    const int lane = threadIdx.x & 63;
    const int b    = blockIdx.x * 4 + w;  // one row per wave
    if (b >= B) return;                   // wave-uniform (exact grid for B%4==0)

    const float E = energy[0];

    // ---- branch-free prelude: all lanes compute (clamped idx), mask later --
    const int jc      = (lane < NP) ? lane : (NP - 1);
    const float tm    = (float)(token_hash[b] % 1000) * 1e-3f;
    const float p     = (float)primes[jc];
    const float sig   = 1.0f / (1.0f + __expf(-rscales[jc]));
    const float freq  = p * (PHI_PI / (float)D) * sig * E;
    const float angle = pshifts[jc] + tm * TWO_PI;
    const float s     = freq * (1.0f + 0.1f * __sinf(angle));

    // ---- norm: weighted sum of squares, cnt_j = D/NP + (j < D%NP) ----------
    const int q = D / NP, r = D % NP;
    float red = (lane < NP) ? (float)(q + (lane < r ? 1 : 0)) * s * s : 0.0f;
    #pragma unroll
    for (int off = 32; off; off >>= 1)
        red += __shfl_xor(red, off, 64);
    const float inv = (red > 0.0f) ? (E / sqrtf(red)) : 1.0f;

    if (NP == 50 && (D & 255) == 0) {
        // ---- pattern entry m (m<25): components s[(4m+c) % 50] * inv -------
        // built in-register via shuffles (sources are lanes 0..49)
        int i0 = (4 * lane) % 50;
        int i1 = i0 + 1; if (i1 >= 50) i1 -= 50;
        int i2 = i0 + 2; if (i2 >= 50) i2 -= 50;
        int i3 = i0 + 3; if (i3 >= 50) i3 -= 50;
        f32x4 v;
        v.x = __shfl(s, i0, 64) * inv;
        v.y = __shfl(s, i1, 64) * inv;
        v.z = __shfl(s, i2, 64) * inv;
        v.w = __shfl(s, i3, 64) * inv;
        if (lane < 25) s_pat[w][lane] = v;
        // no barrier: same wave writes and reads its slot (lgkmcnt-ordered)

        // ---- stream: 64-lane 1024B stores, pattern idx (o%25) incremental --
        f32x4* __restrict__ out4 = reinterpret_cast<f32x4*>(out);
        const int nv = D >> 2;                       // 2048 for D=8192
        const size_t base = (size_t)b * (size_t)nv;
        int rmod = lane;
        if (rmod >= 25) rmod -= 25;
        if (rmod >= 25) rmod -= 25;                  // lane<64 -> <=2 subs
        #pragma unroll 8
        for (int k = lane; k < nv; k += 64) {
            f32x4 pv = s_pat[w][rmod];
            __builtin_nontemporal_store(pv, &out4[base + k]);
            rmod += 14;                              // 64 % 25
            if (rmod >= 25) rmod -= 25;
        }
    } else {
        // generic fallback (not hit for D=8192, NP=50): gather via shuffle
        const size_t rowbase = (size_t)b * (size_t)D;
        for (int i = lane; i < D; i += 64) {
            float sv = __shfl(s, i % NP, 64);
            out[rowbase + i] = sv * inv;
        }
    }
}

extern "C" void kernel_launch(void* const* d_in, const int* in_sizes, int n_in,
                              void* d_out, int out_size, void* d_ws, size_t ws_size,
                              hipStream_t stream) {
    const int*   token_hash = (const int*)  d_in[0];
    const int*   primes     = (const int*)  d_in[1];
    const float* rscales    = (const float*)d_in[2];
    const float* pshifts    = (const float*)d_in[3];
    const float* energy     = (const float*)d_in[4];
    float*       out        = (float*)      d_out;

    const int B  = in_sizes[0];
    const int NP = in_sizes[1];
    const int D  = out_size / B;

    const int blocks = (B + 3) / 4;   // one row per wave, 4 waves per block
    phrs_kernel<<<dim3(blocks), dim3(256), 0, stream>>>(
        token_hash, primes, rscales, pshifts, energy, out, B, D, NP);
}